// Round 1
// baseline (1892.779 us; speedup 1.0000x reference)
//
#include <hip/hip_runtime.h>
#include <hip/hip_fp16.h>

#define BB 256
#define TT 2000
#define HH 100
#define II 4

static constexpr float kC1 = 0.9f;   // 1 - dt/tau
static constexpr float kC2 = 0.1f;   // dt/tau
static constexpr float kEPS = 1e-5f;

// ---------------------------------------------------------------------------
// Kernel 1: per-batch sequential scan. One block (128 thr = 2 waves) per batch.
// Thread j owns channel j; W_hidden column j in registers; tanh(h) broadcast
// through double-buffered LDS; sigma/x prefetched one step ahead.
// Writes: out_buf (fp16, [B,T,H]), per-batch BN partial sums, h_last -> d_out.
// ---------------------------------------------------------------------------
__global__ __launch_bounds__(128) void crnn_scan_kernel(
    const float* __restrict__ x, const float* __restrict__ Win,
    const float* __restrict__ Wh, const float* __restrict__ sigma,
    __half* __restrict__ out_buf, float* __restrict__ partials,
    float* __restrict__ d_out /* h_last stored at offset B*T */)
{
    const int b = blockIdx.x;
    const int j = threadIdx.x;
    const int jc = j < HH ? j : (HH - 1);   // clamp for safe addresses
    const bool act = j < HH;

    __shared__ float th[2][128];

    // W_hidden column j in registers (100 VGPRs, fully unrolled indexing)
    float wcol[HH];
#pragma unroll
    for (int hh = 0; hh < HH; ++hh) wcol[hh] = Wh[hh * HH + jc];
    const float win0 = Win[0 * HH + jc];
    const float win1 = Win[1 * HH + jc];
    const float win2 = Win[2 * HH + jc];
    const float win3 = Win[3 * HH + jc];

    const float* sig = sigma + ((size_t)b * TT) * HH + jc;
    const float* xp  = x + (size_t)b * TT * II;
    __half* op = out_buf + ((size_t)b * TT) * HH + jc;

    float h = 0.f, sum = 0.f, sq = 0.f;
    float  s_cur = sig[0];
    float4 x_cur = *(const float4*)xp;

    for (int t = 0; t < TT; ++t) {
        // prefetch next step's sigma/x (latency hides under the matvec)
        const int tn = (t + 1 < TT) ? (t + 1) : t;
        const float  s_nxt = sig[(size_t)tn * HH];
        const float4 x_nxt = *(const float4*)(xp + (size_t)tn * II);

        const float thj = tanhf(h);
        th[t & 1][j] = thj;
        __syncthreads();   // one barrier per step (double-buffered th)

        // matvec: acc = sum_h th[h] * Wh[h][j]; 25 broadcast b128 reads,
        // 4 independent FMA chains.
        const float4* tb = (const float4*)(&th[t & 1][0]);
        float a0 = 0.f, a1 = 0.f, a2 = 0.f, a3 = 0.f;
#pragma unroll
        for (int kk = 0; kk < HH / 4; ++kk) {
            const float4 t4 = tb[kk];
            a0 = fmaf(t4.x, wcol[4 * kk + 0], a0);
            a1 = fmaf(t4.y, wcol[4 * kk + 1], a1);
            a2 = fmaf(t4.z, wcol[4 * kk + 2], a2);
            a3 = fmaf(t4.w, wcol[4 * kk + 3], a3);
        }
        const float acc = (a0 + a1) + (a2 + a3);
        const float w = x_cur.x * win0 + x_cur.y * win1 +
                        x_cur.z * win2 + x_cur.w * win3;

        h = fmaf(kC1, h, kC2 * (w + acc)) + s_cur;

        if (act) op[(size_t)t * HH] = __float2half(h);
        sum += h;
        sq = fmaf(h, h, sq);

        s_cur = s_nxt;
        x_cur = x_nxt;
    }

    if (act) {
        partials[b * (2 * HH) + j]       = sum;
        partials[b * (2 * HH) + HH + j]  = sq;
        d_out[(size_t)BB * TT + b * HH + j] = h;   // h_last [B,H]
    }
}

// ---------------------------------------------------------------------------
// Kernel 2: fold 256 per-batch partials -> per-channel scale/shift (tiny).
// ---------------------------------------------------------------------------
__global__ void crnn_bnstats_kernel(
    const float* __restrict__ partials, const float* __restrict__ gamma,
    const float* __restrict__ beta, float* __restrict__ scsh)
{
    const int j = threadIdx.x;
    if (j >= HH) return;
    float sum = 0.f, sq = 0.f;
    for (int b = 0; b < BB; ++b) {
        sum += partials[b * (2 * HH) + j];
        sq  += partials[b * (2 * HH) + HH + j];
    }
    const float invN = 1.f / (float)((size_t)BB * TT);
    const float mean = sum * invN;
    const float var  = sq * invN - mean * mean;
    const float sc   = gamma[j] * rsqrtf(var + kEPS);
    scsh[j]      = sc;
    scsh[HH + j] = fmaf(-mean, sc, beta[j]);
}

// ---------------------------------------------------------------------------
// Kernel 3: y[b,t] = sum_h tanh(v*sc+sh) * fc_w[h] + fc_b. Wave per row,
// lane l covers h=l and h=l+64; shuffle tree reduce.
// ---------------------------------------------------------------------------
__global__ __launch_bounds__(256) void crnn_out_kernel(
    const __half* __restrict__ out_buf, const float* __restrict__ scsh,
    const float* __restrict__ fcw, const float* __restrict__ fcb,
    float* __restrict__ out)
{
    const int lane = threadIdx.x & 63;
    const int wid  = blockIdx.x * (blockDim.x >> 6) + (threadIdx.x >> 6);
    const int nw   = gridDim.x * (blockDim.x >> 6);
    const int h2   = lane + 64;
    const bool has2 = h2 < HH;

    const float sc1 = scsh[lane], sh1 = scsh[HH + lane], f1 = fcw[lane];
    float sc2 = 0.f, sh2 = 0.f, f2 = 0.f;
    if (has2) { sc2 = scsh[h2]; sh2 = scsh[HH + h2]; f2 = fcw[h2]; }
    const float bias = fcb[0];

    const long nrows = (long)BB * TT;
    for (long r = wid; r < nrows; r += nw) {
        const __half* row = out_buf + r * HH;
        const float v1 = __half2float(row[lane]);
        float acc = tanhf(fmaf(v1, sc1, sh1)) * f1;
        if (has2) {
            const float v2 = __half2float(row[h2]);
            acc = fmaf(tanhf(fmaf(v2, sc2, sh2)), f2, acc);
        }
#pragma unroll
        for (int o = 32; o >= 1; o >>= 1) acc += __shfl_xor(acc, o, 64);
        if (lane == 0) out[r] = acc + bias;
    }
}

// ---------------------------------------------------------------------------
extern "C" void kernel_launch(void* const* d_in, const int* in_sizes, int n_in,
                              void* d_out, int out_size, void* d_ws, size_t ws_size,
                              hipStream_t stream)
{
    const float* x     = (const float*)d_in[0];
    const float* Win   = (const float*)d_in[1];
    const float* Wh    = (const float*)d_in[2];
    const float* sigma = (const float*)d_in[3];
    const float* gamma = (const float*)d_in[4];
    const float* beta  = (const float*)d_in[5];
    const float* fcw   = (const float*)d_in[6];
    const float* fcb   = (const float*)d_in[7];
    float* out = (float*)d_out;

    char* ws = (char*)d_ws;
    __half* out_buf = (__half*)ws;                                   // B*T*H fp16 = 102,400,000 B
    float* partials = (float*)(ws + (size_t)BB * TT * HH * sizeof(__half));
    float* scsh     = (float*)((char*)partials + (size_t)BB * 2 * HH * sizeof(float));

    crnn_scan_kernel<<<BB, 128, 0, stream>>>(x, Win, Wh, sigma, out_buf, partials, out);
    crnn_bnstats_kernel<<<1, 128, 0, stream>>>(partials, gamma, beta, scsh);
    crnn_out_kernel<<<2048, 256, 0, stream>>>(out_buf, scsh, fcw, fcb, out);
}

// Round 2
// 1428.285 us; speedup vs baseline: 1.3252x; 1.3252x over previous
//
#include <hip/hip_runtime.h>
#include <hip/hip_fp16.h>

#define BB 256
#define TT 2000
#define HH 100
#define II 4
#define KP 28   // padded k-slice stride (25 valid + 3 zero)

static constexpr float kC1 = 0.9f;   // 1 - dt/tau
static constexpr float kC2 = 0.1f;   // dt/tau
static constexpr float kEPS = 1e-5f;

// tanh via v_exp_f32 + v_rcp_f32 (~25 cyc, err ~1e-7 rel — far under threshold)
__device__ __forceinline__ float fast_tanh(float x) {
    const float xc = fminf(fmaxf(x, -15.f), 15.f);
    const float e  = __builtin_amdgcn_exp2f(xc * 2.88539008177793f); // 2*log2(e)
    return (e - 1.f) * __builtin_amdgcn_rcpf(e + 1.f);
}

// ---------------------------------------------------------------------------
// Kernel 1: per-batch scan. 512 thr = 8 waves. thread=(j=tid>>2, kg=tid&3).
// W_hidden k-slice [kg*25, kg*25+25) of column j in 7 named float4 registers.
// tanh(h) broadcast via double-buffered LDS (1 barrier/step); quad shfl reduce.
// ---------------------------------------------------------------------------
__global__ __launch_bounds__(512) void crnn_scan_kernel(
    const float* __restrict__ x, const float* __restrict__ Win,
    const float* __restrict__ Wh, const float* __restrict__ sigma,
    __half* __restrict__ out_buf, float* __restrict__ partials,
    float* __restrict__ d_out /* h_last at offset B*T */)
{
    const int b   = blockIdx.x;
    const int tid = threadIdx.x;
    const int j   = tid >> 2;          // 0..127 (channel)
    const int kg  = tid & 3;           // k-slice group
    const bool act = (j < HH);
    const int jc  = act ? j : (HH - 1);

    __shared__ float4 thb[2][4 * KP / 4];   // [2][28] float4 = 2 x 112 floats
    {   // zero-init (pads must be 0; LDS starts as garbage)
        float* ths = (float*)thb;
        for (int i = tid; i < 2 * 4 * KP; i += 512) ths[i] = 0.f;
    }

    // W_hidden slice: rows k0..k0+24, column jc -> 7 float4 (pad lanes = 0)
    const int k0 = kg * 25;
    auto ldw = [&](int i) -> float { return (i < 25) ? Wh[(k0 + i) * HH + jc] : 0.f; };
    const float4 wc0 = make_float4(ldw( 0), ldw( 1), ldw( 2), ldw( 3));
    const float4 wc1 = make_float4(ldw( 4), ldw( 5), ldw( 6), ldw( 7));
    const float4 wc2 = make_float4(ldw( 8), ldw( 9), ldw(10), ldw(11));
    const float4 wc3 = make_float4(ldw(12), ldw(13), ldw(14), ldw(15));
    const float4 wc4 = make_float4(ldw(16), ldw(17), ldw(18), ldw(19));
    const float4 wc5 = make_float4(ldw(20), ldw(21), ldw(22), ldw(23));
    const float4 wc6 = make_float4(ldw(24), 0.f, 0.f, 0.f);

    const float win0 = Win[0 * HH + jc];
    const float win1 = Win[1 * HH + jc];
    const float win2 = Win[2 * HH + jc];
    const float win3 = Win[3 * HH + jc];

    const float* sig = sigma + (size_t)b * TT * HH + jc;
    const float* xp  = x + (size_t)b * TT * II;
    __half* op = out_buf + (size_t)b * TT * HH + jc;
    const int wslot = (jc / 25) * KP + (jc % 25);

    float h = 0.f, bsum = 0.f, bsq = 0.f;
    float  s_cur = sig[0];
    float4 x_cur = *(const float4*)xp;

    __syncthreads();   // LDS zeros visible

    for (int t = 0; t < TT; ++t) {
        // prefetch next step's sigma/x (hidden under the matvec)
        const int tn = (t + 1 < TT) ? (t + 1) : t;
        const float  s_nxt = sig[(size_t)tn * HH];
        const float4 x_nxt = *(const float4*)(xp + (size_t)tn * II);

        const float thj = fast_tanh(h);            // all lanes (h replicated)
        if (kg == 0 && act) ((float*)thb[t & 1])[wslot] = thj;
        __syncthreads();

        // slice dot: 7 broadcast ds_read_b128 + 28 FMA in 4 chains
        const float4* tb = (const float4*)&thb[t & 1][kg * (KP / 4)];
        const float4 t0 = tb[0], t1 = tb[1], t2 = tb[2], t3 = tb[3];
        const float4 t4 = tb[4], t5 = tb[5], t6 = tb[6];
        float a0 = t0.x * wc0.x, a1 = t0.y * wc0.y;
        float a2 = t0.z * wc0.z, a3 = t0.w * wc0.w;
        a0 = fmaf(t1.x, wc1.x, a0); a1 = fmaf(t1.y, wc1.y, a1);
        a2 = fmaf(t1.z, wc1.z, a2); a3 = fmaf(t1.w, wc1.w, a3);
        a0 = fmaf(t2.x, wc2.x, a0); a1 = fmaf(t2.y, wc2.y, a1);
        a2 = fmaf(t2.z, wc2.z, a2); a3 = fmaf(t2.w, wc2.w, a3);
        a0 = fmaf(t3.x, wc3.x, a0); a1 = fmaf(t3.y, wc3.y, a1);
        a2 = fmaf(t3.z, wc3.z, a2); a3 = fmaf(t3.w, wc3.w, a3);
        a0 = fmaf(t4.x, wc4.x, a0); a1 = fmaf(t4.y, wc4.y, a1);
        a2 = fmaf(t4.z, wc4.z, a2); a3 = fmaf(t4.w, wc4.w, a3);
        a0 = fmaf(t5.x, wc5.x, a0); a1 = fmaf(t5.y, wc5.y, a1);
        a2 = fmaf(t5.z, wc5.z, a2); a3 = fmaf(t5.w, wc5.w, a3);
        a0 = fmaf(t6.x, wc6.x, a0); a1 = fmaf(t6.y, wc6.y, a1);
        a2 = fmaf(t6.z, wc6.z, a2); a3 = fmaf(t6.w, wc6.w, a3);
        float sum = (a0 + a1) + (a2 + a3);
        sum += __shfl_xor(sum, 1, 64);             // quad reduce over kg
        sum += __shfl_xor(sum, 2, 64);             // all 4 lanes get full dot

        const float w = x_cur.x * win0 + x_cur.y * win1 +
                        x_cur.z * win2 + x_cur.w * win3;
        h = fmaf(kC1, h, kC2 * (w + sum)) + s_cur;  // replicated across quad

        if (kg == 0 && act) op[(size_t)t * HH] = __float2half(h);
        bsum += h;
        bsq = fmaf(h, h, bsq);

        s_cur = s_nxt;
        x_cur = x_nxt;
    }

    if (kg == 0 && act) {
        partials[b * (2 * HH) + jc]      = bsum;
        partials[b * (2 * HH) + HH + jc] = bsq;
        d_out[(size_t)BB * TT + b * HH + jc] = h;   // h_last [B,H]
    }
}

// ---------------------------------------------------------------------------
// Kernel 2: fold per-batch partials -> per-channel scale/shift. Quad-split.
// ---------------------------------------------------------------------------
__global__ __launch_bounds__(512) void crnn_bnstats_kernel(
    const float* __restrict__ partials, const float* __restrict__ gamma,
    const float* __restrict__ beta, float* __restrict__ scsh)
{
    const int tid = threadIdx.x;
    const int j = tid >> 2, c = tid & 3;
    if (j >= HH) return;
    float sum = 0.f, sq = 0.f;
    for (int b = c; b < BB; b += 4) {
        sum += partials[b * 2 * HH + j];
        sq  += partials[b * 2 * HH + HH + j];
    }
    sum += __shfl_xor(sum, 1, 64); sum += __shfl_xor(sum, 2, 64);
    sq  += __shfl_xor(sq,  1, 64); sq  += __shfl_xor(sq,  2, 64);
    if (c == 0) {
        const float invN = 1.f / (float)((long)BB * TT);
        const float mean = sum * invN;
        const float var  = sq * invN - mean * mean;
        const float sc   = gamma[j] * rsqrtf(var + kEPS);
        scsh[j]      = sc;
        scsh[HH + j] = fmaf(-mean, sc, beta[j]);
    }
}

// ---------------------------------------------------------------------------
// Kernel 3: y[r] = sum_h tanh(v*sc+sh)*fcw[h] + fcb. Wave per row; lane l
// covers h=2l,2l+1 via one half2 load; 6-level shuffle reduce.
// ---------------------------------------------------------------------------
__global__ __launch_bounds__(256) void crnn_out_kernel(
    const __half* __restrict__ buf, const float* __restrict__ scsh,
    const float* __restrict__ fcw, const float* __restrict__ fcb,
    float* __restrict__ out)
{
    const int lane = threadIdx.x & 63;
    const int wid  = blockIdx.x * (blockDim.x >> 6) + (threadIdx.x >> 6);
    const int nw   = gridDim.x * (blockDim.x >> 6);
    const bool a   = lane < HH / 2;
    const int h0 = 2 * lane, h1 = 2 * lane + 1;
    float sc0 = 0.f, sh0 = 0.f, f0 = 0.f, sc1 = 0.f, sh1 = 0.f, f1 = 0.f;
    if (a) {
        sc0 = scsh[h0]; sh0 = scsh[HH + h0]; f0 = fcw[h0];
        sc1 = scsh[h1]; sh1 = scsh[HH + h1]; f1 = fcw[h1];
    }
    const float bias = fcb[0];
    const long nrows = (long)BB * TT;
    for (long r = wid; r < nrows; r += nw) {
        float acc = 0.f;
        if (a) {
            const __half2 v = *(const __half2*)(buf + r * HH + h0);
            const float2 vf = __half22float2(v);
            acc = fast_tanh(fmaf(vf.x, sc0, sh0)) * f0
                + fast_tanh(fmaf(vf.y, sc1, sh1)) * f1;
        }
#pragma unroll
        for (int o = 32; o >= 1; o >>= 1) acc += __shfl_xor(acc, o, 64);
        if (lane == 0) out[r] = acc + bias;
    }
}

// ---------------------------------------------------------------------------
extern "C" void kernel_launch(void* const* d_in, const int* in_sizes, int n_in,
                              void* d_out, int out_size, void* d_ws, size_t ws_size,
                              hipStream_t stream)
{
    const float* x     = (const float*)d_in[0];
    const float* Win   = (const float*)d_in[1];
    const float* Wh    = (const float*)d_in[2];
    const float* sigma = (const float*)d_in[3];
    const float* gamma = (const float*)d_in[4];
    const float* beta  = (const float*)d_in[5];
    const float* fcw   = (const float*)d_in[6];
    const float* fcb   = (const float*)d_in[7];
    float* out = (float*)d_out;

    char* ws = (char*)d_ws;
    __half* out_buf = (__half*)ws;                                   // B*T*H fp16
    float* partials = (float*)(ws + (size_t)BB * TT * HH * sizeof(__half));
    float* scsh     = (float*)((char*)partials + (size_t)BB * 2 * HH * sizeof(float));

    crnn_scan_kernel<<<BB, 512, 0, stream>>>(x, Win, Wh, sigma, out_buf, partials, out);
    crnn_bnstats_kernel<<<1, 512, 0, stream>>>(partials, gamma, beta, scsh);
    crnn_out_kernel<<<2048, 256, 0, stream>>>(out_buf, scsh, fcw, fcb, out);
}

// Round 3
// 1082.595 us; speedup vs baseline: 1.7484x; 1.3193x over previous
//
#include <hip/hip_runtime.h>
#include <hip/hip_fp16.h>

#define BB 256
#define TT 2000
#define HH 100
#define II 4
#define KP 28            // padded k-slice stride (25 valid + 3 zero)
#define CH 16            // time-chunk (register-buffered I/O)
#define NCHUNK (TT / CH) // 125

typedef __attribute__((ext_vector_type(8))) unsigned short ushort8_t;

static constexpr float kC1 = 0.9f;   // 1 - dt/tau
static constexpr float kC2 = 0.1f;   // dt/tau
static constexpr float kEPS = 1e-5f;

// tanh via v_exp_f32 + v_rcp_f32 (~25 cyc, rel err ~1e-7)
__device__ __forceinline__ float fast_tanh(float x) {
    const float xc = fminf(fmaxf(x, -15.f), 15.f);
    const float e  = __builtin_amdgcn_exp2f(xc * 2.88539008177793f); // 2*log2(e)
    return (e - 1.f) * __builtin_amdgcn_rcpf(e + 1.f);
}

// ---------------------------------------------------------------------------
// Kernel 1: per-batch scan. 512 thr; thread=(j=tid>>2, kg=tid&3).
// Raw s_barrier (no vmcnt drain!) + chunked register-double-buffered sigma/w
// prefetch + packed fp16 chunk stores to [B][H][T] layout.
// ---------------------------------------------------------------------------
__global__ __launch_bounds__(512) void crnn_scan_kernel(
    const float* __restrict__ x, const float* __restrict__ Win,
    const float* __restrict__ Wh, const float* __restrict__ sigma,
    __half* __restrict__ out_buf, float* __restrict__ partials,
    float* __restrict__ d_out /* h_last at offset B*T */)
{
    const int b   = blockIdx.x;
    const int tid = threadIdx.x;
    const int j   = tid >> 2;          // channel 0..127
    const int kg  = tid & 3;           // k-slice group
    const bool act = (j < HH);
    const int jc  = act ? j : (HH - 1);

    __shared__ float4 thb[2][4 * KP / 4];   // [2][28] float4
    {   // zero-init (pad slots must read as 0)
        float* ths = (float*)thb;
        for (int i = tid; i < 2 * 4 * KP; i += 512) ths[i] = 0.f;
    }

    // W_hidden k-slice [kg*25, kg*25+25) of column jc in 7 named float4s
    const int k0 = kg * 25;
    auto ldw = [&](int i) -> float { return (i < 25) ? Wh[(k0 + i) * HH + jc] : 0.f; };
    const float4 wc0 = make_float4(ldw( 0), ldw( 1), ldw( 2), ldw( 3));
    const float4 wc1 = make_float4(ldw( 4), ldw( 5), ldw( 6), ldw( 7));
    const float4 wc2 = make_float4(ldw( 8), ldw( 9), ldw(10), ldw(11));
    const float4 wc3 = make_float4(ldw(12), ldw(13), ldw(14), ldw(15));
    const float4 wc4 = make_float4(ldw(16), ldw(17), ldw(18), ldw(19));
    const float4 wc5 = make_float4(ldw(20), ldw(21), ldw(22), ldw(23));
    const float4 wc6 = make_float4(ldw(24), 0.f, 0.f, 0.f);

    const float win0 = Win[0 * HH + jc];
    const float win1 = Win[1 * HH + jc];
    const float win2 = Win[2 * HH + jc];
    const float win3 = Win[3 * HH + jc];

    const float* sig = sigma + (size_t)b * TT * HH + jc;
    const float* xp  = x + (size_t)b * TT * II;
    __half* op = out_buf + ((size_t)b * HH + jc) * TT;   // [B][H][T]
    const int wslot = (jc / 25) * KP + (jc % 25);

    float h = 0.f, bsum = 0.f, bsq = 0.f;

    float sA[CH], wA[CH], sB[CH], wB[CH];

    // issue chunk loads (no waits here; compiler inserts counted vmcnt at use)
    auto loadc = [&](int t0, float (&ss)[CH], float (&ww)[CH]) {
#pragma unroll
        for (int i = 0; i < CH; ++i) ss[i] = sig[(size_t)(t0 + i) * HH];
#pragma unroll
        for (int i = 0; i < CH; ++i) {
            const float4 xv = *(const float4*)(xp + (size_t)(t0 + i) * II);
            ww[i] = xv.x * win0 + xv.y * win1 + xv.z * win2 + xv.w * win3;
        }
    };

    auto run_chunk = [&](int t0, const float (&ss)[CH], const float (&ww)[CH]) {
        unsigned int hw[CH / 2];
#pragma unroll
        for (int i = 0; i < CH; ++i) {   // t0 even -> buffer index = i&1
            const float thj = fast_tanh(h);
            if (kg == 0 && act) ((float*)thb[i & 1])[wslot] = thj;
            // raw barrier: LDS-visibility wait only, NO vmcnt drain
            asm volatile("s_waitcnt lgkmcnt(0)" ::: "memory");
            __builtin_amdgcn_s_barrier();
            asm volatile("" ::: "memory");

            const float4* tb = (const float4*)&thb[i & 1][kg * (KP / 4)];
            const float4 t0v = tb[0], t1v = tb[1], t2v = tb[2], t3v = tb[3];
            const float4 t4v = tb[4], t5v = tb[5], t6v = tb[6];
            float a0 = t0v.x * wc0.x, a1 = t0v.y * wc0.y;
            float a2 = t0v.z * wc0.z, a3 = t0v.w * wc0.w;
            a0 = fmaf(t1v.x, wc1.x, a0); a1 = fmaf(t1v.y, wc1.y, a1);
            a2 = fmaf(t1v.z, wc1.z, a2); a3 = fmaf(t1v.w, wc1.w, a3);
            a0 = fmaf(t2v.x, wc2.x, a0); a1 = fmaf(t2v.y, wc2.y, a1);
            a2 = fmaf(t2v.z, wc2.z, a2); a3 = fmaf(t2v.w, wc2.w, a3);
            a0 = fmaf(t3v.x, wc3.x, a0); a1 = fmaf(t3v.y, wc3.y, a1);
            a2 = fmaf(t3v.z, wc3.z, a2); a3 = fmaf(t3v.w, wc3.w, a3);
            a0 = fmaf(t4v.x, wc4.x, a0); a1 = fmaf(t4v.y, wc4.y, a1);
            a2 = fmaf(t4v.z, wc4.z, a2); a3 = fmaf(t4v.w, wc4.w, a3);
            a0 = fmaf(t5v.x, wc5.x, a0); a1 = fmaf(t5v.y, wc5.y, a1);
            a2 = fmaf(t5v.z, wc5.z, a2); a3 = fmaf(t5v.w, wc5.w, a3);
            a0 = fmaf(t6v.x, wc6.x, a0); a1 = fmaf(t6v.y, wc6.y, a1);
            a2 = fmaf(t6v.z, wc6.z, a2); a3 = fmaf(t6v.w, wc6.w, a3);
            float sum = (a0 + a1) + (a2 + a3);
            sum += __shfl_xor(sum, 1, 64);   // quad reduce over kg
            sum += __shfl_xor(sum, 2, 64);

            h = fmaf(kC1, h, kC2 * (ww[i] + sum)) + ss[i];

            const unsigned int hb = (unsigned int)__half_as_ushort(__float2half(h));
            if ((i & 1) == 0) hw[i >> 1] = hb; else hw[i >> 1] |= hb << 16;
            bsum += h;
            bsq = fmaf(h, h, bsq);
        }
        if (kg == 0 && act) {   // 32B contiguous fp16 store, [B][H][T]
            uint4* dst = (uint4*)(op + t0);
            dst[0] = make_uint4(hw[0], hw[1], hw[2], hw[3]);
            dst[1] = make_uint4(hw[4], hw[5], hw[6], hw[7]);
        }
    };

    __syncthreads();            // LDS zero-init visible (one-time)
    loadc(0, sA, wA);
    for (int c = 0; c < NCHUNK; ++c) {
        const int t0 = c * CH;
        if ((c & 1) == 0) {
            if (c + 1 < NCHUNK) loadc(t0 + CH, sB, wB);
            run_chunk(t0, sA, wA);
        } else {
            if (c + 1 < NCHUNK) loadc(t0 + CH, sA, wA);
            run_chunk(t0, sB, wB);
        }
    }

    if (kg == 0 && act) {
        partials[b * (2 * HH) + jc]      = bsum;
        partials[b * (2 * HH) + HH + jc] = bsq;
        d_out[(size_t)BB * TT + b * HH + jc] = h;   // h_last [B,H]
    }
}

// ---------------------------------------------------------------------------
// Kernel 2: fold per-batch partials -> per-channel scale/shift. Tiny.
// ---------------------------------------------------------------------------
__global__ __launch_bounds__(512) void crnn_bnstats_kernel(
    const float* __restrict__ partials, const float* __restrict__ gamma,
    const float* __restrict__ beta, float* __restrict__ scsh)
{
    const int tid = threadIdx.x;
    const int j = tid >> 2, c = tid & 3;
    if (j >= HH) return;
    float sum = 0.f, sq = 0.f;
    for (int b = c; b < BB; b += 4) {
        sum += partials[b * 2 * HH + j];
        sq  += partials[b * 2 * HH + HH + j];
    }
    sum += __shfl_xor(sum, 1, 64); sum += __shfl_xor(sum, 2, 64);
    sq  += __shfl_xor(sq,  1, 64); sq  += __shfl_xor(sq,  2, 64);
    if (c == 0) {
        const float invN = 1.f / (float)((long)BB * TT);
        const float mean = sum * invN;
        const float var  = sq * invN - mean * mean;
        const float sc   = gamma[j] * rsqrtf(var + kEPS);
        scsh[j]      = sc;
        scsh[HH + j] = fmaf(-mean, sc, beta[j]);
    }
}

// ---------------------------------------------------------------------------
// Kernel 3: [B][H][T] layout -> thread owns 8 consecutive t's (16B loads),
// loops h with uniform (s_load) BN constants. Fully coalesced, no shuffles.
// ---------------------------------------------------------------------------
__global__ __launch_bounds__(256) void crnn_out_kernel(
    const __half* __restrict__ buf, const float* __restrict__ scsh,
    const float* __restrict__ fcw, const float* __restrict__ fcb,
    float* __restrict__ out)
{
    const int b   = blockIdx.x;
    const int tid = threadIdx.x;
    const bool a  = (tid < TT / 8);     // 250 active
    const int t0  = tid * 8;
    const __half* bp = buf + (size_t)b * HH * TT + t0;
    const float bias = fcb[0];

    float acc[8] = {0.f, 0.f, 0.f, 0.f, 0.f, 0.f, 0.f, 0.f};
    for (int hh = 0; hh < HH; ++hh) {
        const float sc = scsh[hh], sh = scsh[HH + hh], fw = fcw[hh];
        if (a) {
            const ushort8_t v = *(const ushort8_t*)(bp + (size_t)hh * TT);
#pragma unroll
            for (int e = 0; e < 8; ++e) {
                const float vf = __half2float(__ushort_as_half((unsigned short)v[e]));
                acc[e] = fmaf(fast_tanh(fmaf(vf, sc, sh)), fw, acc[e]);
            }
        }
    }
    if (a) {
        float4* o = (float4*)(out + (size_t)b * TT + t0);
        o[0] = make_float4(acc[0] + bias, acc[1] + bias, acc[2] + bias, acc[3] + bias);
        o[1] = make_float4(acc[4] + bias, acc[5] + bias, acc[6] + bias, acc[7] + bias);
    }
}

// ---------------------------------------------------------------------------
extern "C" void kernel_launch(void* const* d_in, const int* in_sizes, int n_in,
                              void* d_out, int out_size, void* d_ws, size_t ws_size,
                              hipStream_t stream)
{
    const float* x     = (const float*)d_in[0];
    const float* Win   = (const float*)d_in[1];
    const float* Wh    = (const float*)d_in[2];
    const float* sigma = (const float*)d_in[3];
    const float* gamma = (const float*)d_in[4];
    const float* beta  = (const float*)d_in[5];
    const float* fcw   = (const float*)d_in[6];
    const float* fcb   = (const float*)d_in[7];
    float* out = (float*)d_out;

    char* ws = (char*)d_ws;
    __half* out_buf = (__half*)ws;                                   // B*H*T fp16
    float* partials = (float*)(ws + (size_t)BB * TT * HH * sizeof(__half));
    float* scsh     = (float*)((char*)partials + (size_t)BB * 2 * HH * sizeof(float));

    crnn_scan_kernel<<<BB, 512, 0, stream>>>(x, Win, Wh, sigma, out_buf, partials, out);
    crnn_bnstats_kernel<<<1, 512, 0, stream>>>(partials, gamma, beta, scsh);
    crnn_out_kernel<<<BB, 256, 0, stream>>>(out_buf, scsh, fcw, fcb, out);
}